// Round 6
// baseline (226.539 us; speedup 1.0000x reference)
//
#include <hip/hip_runtime.h>

#define N_NODES 100000
#define N_EDGES 3200000
#define N_GRAPHS 512
#define VOCAB 128
#define HID 16
#define LABELS 10
#define CAP 64                  // main slots/node
#define EXT 32                  // overflow slots/node (cold)
#define TS 17                   // LDS table row stride (bank de-alias)

// ---- binned CSR build ----
#define BSH 9                   // 512 nodes per bucket (R6: 4x longer runs)
#define BNODES 512
#define NB 196                  // ceil(N_NODES/512)
#define NSUB 8                  // XCD-local sub-tails (blockIdx&7 ~ XCD)
#define SUBCAP 4096             // entries per (bucket,sub): mean ~2040, +45 sigma
#define BREG (BNODES * CAP)     // 32768 ints per bucket region == NSUB*SUBCAP
#define EPT 16                  // edges per thread in k_bin
#define BCHUNK 4096             // edges per k_bin block (256 thr x 16)

typedef int vint4 __attribute__((ext_vector_type(4)));  // native vec for NT loads

__device__ __forceinline__ unsigned bf16rne(float f) {
    unsigned u = __float_as_uint(f);
    return (u + 0x7fffu + ((u >> 16) & 1u)) >> 16;
}
__device__ __forceinline__ float bf16lo(unsigned p) { return __uint_as_float(p << 16); }
__device__ __forceinline__ float bf16hi(unsigned p) { return __uint_as_float(p & 0xffff0000u); }

// Pass 1: bin edges by dst>>9 via LDS counting sort, write bucket-sorted runs.
// R5 lesson: with 128-node buckets, runs were 5.2 entries (~1.3 int4) -> a
// wave's 64 lanes still scattered to 64 dests and sectors evicted half-full
// (WRITE 2.4x payload, 1.1 TB/s effective). 512-node buckets -> ~21-entry
// runs (~5 int4/lane, consecutive) -> dense full sectors, write amp ~1.1.
// LDS stays 17.7 KB -> 8 blocks/CU (R2's occupancy fix AND long runs).
__global__ void k_bin(const int* __restrict__ src, const int* __restrict__ dst,
                      int* __restrict__ bcur, int* __restrict__ ebuf) {
    __shared__ int scnt[NB];              // histogram, then exclusive prefix (in-place)
    __shared__ int gbase[NB];             // absolute (padded) ebuf base for this block's run
    __shared__ int sent[BCHUNK];          // compact sorted entries
    int t = threadIdx.x;
    int sub = blockIdx.x & (NSUB - 1);
    for (int i = t; i < NB; i += 256) scnt[i] = 0;
    int e0 = blockIdx.x * BCHUNK + t * EPT;
    bool val = e0 < N_EDGES;              // N_EDGES % 16 == 0 -> whole-thread validity
    int dd[EPT], ss[EPT];
    if (val) {
        const vint4* dp = (const vint4*)(dst + e0);
        const vint4* sp = (const vint4*)(src + e0);
#pragma unroll
        for (int q = 0; q < 4; ++q) {
            vint4 d4 = __builtin_nontemporal_load(dp + q);
            vint4 s4 = __builtin_nontemporal_load(sp + q);
            dd[q * 4 + 0] = d4.x; dd[q * 4 + 1] = d4.y; dd[q * 4 + 2] = d4.z; dd[q * 4 + 3] = d4.w;
            ss[q * 4 + 0] = s4.x; ss[q * 4 + 1] = s4.y; ss[q * 4 + 2] = s4.z; ss[q * 4 + 3] = s4.w;
        }
    }
    __syncthreads();                      // scnt zeroed
    int rk[EPT];
    if (val) {
#pragma unroll
        for (int j = 0; j < EPT; ++j) rk[j] = atomicAdd(&scnt[dd[j] >> BSH], 1);
    }
    __syncthreads();                      // histogram complete
    // single-wave exclusive scan: lane t owns buckets [4t, 4t+4); NB = 49*4
    if (t < 64) {
        int b0 = t * 4;
        int c0 = 0, c1 = 0, c2 = 0, c3 = 0;
        if (b0 < NB) { c0 = scnt[b0]; c1 = scnt[b0 + 1]; c2 = scnt[b0 + 2]; c3 = scnt[b0 + 3]; }
        int lsum = c0 + c1 + c2 + c3;
        int x = lsum;
#pragma unroll
        for (int d = 1; d < 64; d <<= 1) {
            int y = __shfl_up(x, d);
            if (t >= d) x += y;
        }
        int excl = x - lsum;              // exclusive base for this lane's buckets
        if (b0 < NB) {
            int cc[4] = {c0, c1, c2, c3};
#pragma unroll
            for (int q = 0; q < 4; ++q) {
                int b = b0 + q;
                scnt[b] = excl;           // in-place: now the exclusive prefix
                if (cc[q] > 0) {
                    int r = (cc[q] + 3) & ~3;            // padded reservation (x4)
                    int g = atomicAdd(&bcur[b * NSUB + sub], r);
                    gbase[b] = b * BREG + sub * SUBCAP + g;   // 16B-aligned
                }
                excl += cc[q];
            }
        }
    }
    __syncthreads();                      // prefix/gbase ready
    if (val) {
#pragma unroll
        for (int j = 0; j < EPT; ++j) {
            int d = dd[j], b = d >> BSH;
            sent[scnt[b] + rk[j]] = ((d & (BNODES - 1)) << 17) | ss[j];
        }
    }
    __syncthreads();                      // sorted stage ready
    int nval = N_EDGES - blockIdx.x * BCHUNK;
    if (nval > BCHUNK) nval = BCHUNK;
    for (int b = t; b < NB; b += 256) {   // ~21-entry run per thread, 5 consecutive int4s
        int base = scnt[b];
        int cend = (b + 1 < NB) ? scnt[b + 1] : nval;
        int c = cend - base;
        if (c <= 0) continue;
        int g = gbase[b];
        int lim = b * BREG + (sub + 1) * SUBCAP;
        for (int j = 0; j < c; j += 4) {
            if (g + j + 4 > lim) break;   // overflow guard (P ~ 0)
            int4 v;
            v.x = sent[base + j];
            v.y = (j + 1 < c) ? sent[base + j + 1] : -1;
            v.z = (j + 2 < c) ? sent[base + j + 2] : -1;
            v.w = (j + 3 < c) ? sent[base + j + 3] : -1;
            *(int4*)(ebuf + g + j) = v;   // aligned 16B, line filled by same lane
        }
    }
}

// Pass 2: one block per 512-node bucket. Scatter entries into a 128 KB LDS CSR
// slab (LDS atomics, skipping -1 pad sentinels), then write ONLY the used
// slots (rounded to int4) coalesced. Emits true per-node degree -> cnt.
// Reads its entry region BEFORE overwriting it (same memory, barrier between).
__global__ void k_fill(const int* __restrict__ bcur, int* __restrict__ csrf,
                       int* __restrict__ ext, int* __restrict__ cnt) {
    __shared__ int stage[BREG];                  // 128 KB
    __shared__ int cl[BNODES];                   // 2 KB
    int b = blockIdx.x, t = threadIdx.x;
    int nb0 = b << BSH;
    int nn = N_NODES - nb0; if (nn > BNODES) nn = BNODES;
    for (int i = t; i < BNODES; i += 256) cl[i] = 0;
    __syncthreads();
    const int* ebase = csrf + (size_t)b * BREG;
    for (int sub = 0; sub < NSUB; ++sub) {
        int m = bcur[b * NSUB + sub]; if (m > SUBCAP) m = SUBCAP;
        const int* ep = ebase + sub * SUBCAP;
        for (int i = t; i < m; i += 256) {
            int e2 = ep[i];
            if (e2 == -1) continue;                  // pad sentinel
            int dl = ((unsigned)e2) >> 17, s = e2 & 0x1FFFF;
            int c = atomicAdd(&cl[dl], 1);
            if (c < CAP)            stage[(dl << 6) + c] = s;
            else if (c < CAP + EXT) ext[(size_t)(nb0 + dl) * EXT + (c - CAP)] = s;
            // c >= CAP+EXT unreachable (P ~ 0)
        }
    }
    __syncthreads();
    int4* o4 = (int4*)(csrf + (size_t)b * BREG);
    const int4* s4 = (const int4*)stage;
    for (int dl = t >> 1; dl < BNODES; dl += 128) {  // 2 threads per node
        int m4 = (cl[dl] + 3) >> 2;                  // used int4s (garbage never read)
        for (int j = (t & 1); j < m4; j += 2)
            o4[(dl << 4) + j] = s4[(dl << 4) + j];
    }
    for (int i = t; i < nn; i += 256) cnt[nb0 + i] = cl[i];
}

// deg -> dinv (fp32, systematic dst-side scale) and packed
// xd32[n] = (x[n] << 16) | bf16(dinv[n]) for the per-edge src gather.
__global__ void k_dinv2(const int* __restrict__ cnt, const int* __restrict__ x,
                        float* __restrict__ dinv, unsigned* __restrict__ xd32) {
    int n = blockIdx.x * blockDim.x + threadIdx.x;
    if (n >= N_NODES) return;
    float dv = rsqrtf((float)cnt[n] + 1.0f);   // +1 = self-loop
    dinv[n] = dv;
    xd32[n] = ((unsigned)x[n] << 16) | bf16rne(dv);
}

// table = emb @ W1 (128 x 16)
__global__ void k_table(const float* __restrict__ emb, const float* __restrict__ W1,
                        float* __restrict__ table) {
    int t = blockIdx.x * blockDim.x + threadIdx.x;
    if (t >= VOCAB * HID) return;
    int v = t / HID, k = t % HID;
    float acc = 0.f;
    for (int j = 0; j < HID; ++j) acc += emb[v * HID + j] * W1[j * HID + k];
    table[t] = acc;
}

// FUSED layer-1 aggregation + update, 8 lanes/node (lane k owns features k, k+8).
// 16-wide main loop: two independent {csrf load -> xd32 gather} chains.
__global__ void k_gather_t(const int* __restrict__ cnt, const int* __restrict__ csrf,
                           const int* __restrict__ ext,
                           const unsigned* __restrict__ xd32, const float* __restrict__ dinv,
                           const float* __restrict__ table,
                           const float* __restrict__ b1, const float* __restrict__ W2,
                           unsigned* __restrict__ hws16) {
    __shared__ float tbl[VOCAB * TS];
    __shared__ float sW[HID * HID];
    __shared__ float sb[HID];
    __shared__ float sh[32][HID + 1];
    for (int i = threadIdx.x; i < VOCAB * HID; i += 256)
        tbl[(i / HID) * TS + (i % HID)] = table[i];
    if (threadIdx.x < HID * HID) sW[threadIdx.x] = W2[threadIdx.x];
    if (threadIdx.x < HID) sb[threadIdx.x] = b1[threadIdx.x];
    __syncthreads();
    int t = blockIdx.x * 256 + threadIdx.x;
    int n = t >> 3, k = t & 7, nl = threadIdx.x >> 3;   // 32 node-groups/block
    float dvn = dinv[n];
    unsigned selfp = xd32[n];
    int vs = (selfp >> 16) * TS;
    float a0 = tbl[vs + k] * dvn, a1 = tbl[vs + k + 8] * dvn;   // self-loop
    int c = cnt[n];
    int cm = c < CAP ? c : CAP;
    int lo = n * CAP, hi = lo + cm;
    int i = lo;
    for (; i + 16 <= hi; i += 16) {
        int sa = csrf[i + k];             // chain A
        int sb_ = csrf[i + 8 + k];        // chain B (independent)
        unsigned pa = xd32[sa];
        unsigned pb = xd32[sb_];
#pragma unroll
        for (int j = 0; j < 8; ++j) {
            unsigned pj = __shfl(pa, j, 8);
            float w = bf16lo(pj);
            int v = (pj >> 16) * TS;
            a0 += tbl[v + k] * w;         a1 += tbl[v + k + 8] * w;
        }
#pragma unroll
        for (int j = 0; j < 8; ++j) {
            unsigned pj = __shfl(pb, j, 8);
            float w = bf16lo(pj);
            int v = (pj >> 16) * TS;
            a0 += tbl[v + k] * w;         a1 += tbl[v + k + 8] * w;
        }
    }
    for (; i + 8 <= hi; i += 8) {
        int s = csrf[i + k];
        unsigned p = xd32[s];
#pragma unroll
        for (int j = 0; j < 8; ++j) {
            unsigned pj = __shfl(p, j, 8);
            float w = bf16lo(pj);
            int v = (pj >> 16) * TS;
            a0 += tbl[v + k] * w;         a1 += tbl[v + k + 8] * w;
        }
    }
    for (; i < hi; ++i) {
        unsigned p = xd32[csrf[i]];
        float w = bf16lo(p);
        int v = (p >> 16) * TS;
        a0 += tbl[v + k] * w;             a1 += tbl[v + k + 8] * w;
    }
    if (c > CAP) {                        // rare overflow tail
        int ce = c - CAP; if (ce > EXT) ce = EXT;
        for (int j = 0; j < ce; ++j) {
            unsigned p = xd32[ext[n * EXT + j]];
            float w = bf16lo(p);
            int v = (p >> 16) * TS;
            a0 += tbl[v + k] * w;         a1 += tbl[v + k + 8] * w;
        }
    }
    sh[nl][k]     = fmaxf(a0 * dvn + sb[k], 0.f);      // h1[n,k]
    sh[nl][k + 8] = fmaxf(a1 * dvn + sb[k + 8], 0.f);  // h1[n,k+8]
    __syncthreads();
    float o0 = 0.f, o1 = 0.f;
#pragma unroll
    for (int j = 0; j < HID; ++j) {
        float h = sh[nl][j];
        o0 += h * sW[j * HID + k];
        o1 += h * sW[j * HID + k + 8];
    }
    o0 *= dvn; o1 *= dvn;
    float p0 = __shfl_xor(o0, 1), p1 = __shfl_xor(o1, 1);  // partner features k^1
    if ((k & 1) == 0) {                   // even lane packs (k,k+1) and (k+8,k+9)
        hws16[n * 8 + (k >> 1)]     = (bf16rne(p0) << 16) | bf16rne(o0);
        hws16[n * 8 + 4 + (k >> 1)] = (bf16rne(p1) << 16) | bf16rne(o1);
    }
}

// FUSED layer-2 aggregation + relu + mean-pool accumulation. 4 lanes/node,
// 16-wide main loop (four independent gather chains). Batch sorted -> leader
// lanes reduce graph runs in LDS, one atomicAdd per (run x 4 features).
__global__ void k_gather2(const int* __restrict__ cnt, const int* __restrict__ csrf,
                          const int* __restrict__ ext,
                          const float* __restrict__ dinv, const unsigned* __restrict__ hws16,
                          const int* __restrict__ batch, const float* __restrict__ b2,
                          float* __restrict__ psum, float* __restrict__ pcnt) {
    __shared__ float sh[64 * 17];              // 64 nodes x 16 feats, pad 17
    __shared__ int   sg[64];                   // graph id per node slot (-1 invalid)
    __shared__ float sb2[16];
    int idx = blockIdx.x * 256 + threadIdx.x;
    int n = idx >> 2, q = idx & 3, ln = threadIdx.x >> 2;
    bool valid = n < N_NODES;
    if (threadIdx.x < 16) sb2[threadIdx.x] = b2[threadIdx.x];
    if (q == 0) sg[ln] = valid ? batch[n] : -1;
    __syncthreads();
    float hx = 0.f, hy = 0.f, hz = 0.f, hw = 0.f;
    if (valid) {
        const uint2* hp = (const uint2*)hws16; // 4 uint2 per node row
        uint2 u = hp[n * 4 + q];
        float ax = bf16lo(u.x), ay = bf16hi(u.x), az = bf16lo(u.y), aw = bf16hi(u.y);
        int c = cnt[n];
        int cm = c < CAP ? c : CAP;
        int lo = n * CAP, hi = lo + cm;
        int i = lo;
        for (; i + 16 <= hi; i += 16) {
            int sA = csrf[i + q],      sB = csrf[i + 4 + q];
            int sC = csrf[i + 8 + q],  sD = csrf[i + 12 + q];
#pragma unroll
            for (int j = 0; j < 4; ++j) {
                int sj = __shfl(sA, j, 4);
                uint2 uu = hp[sj * 4 + q];
                ax += bf16lo(uu.x); ay += bf16hi(uu.x); az += bf16lo(uu.y); aw += bf16hi(uu.y);
            }
#pragma unroll
            for (int j = 0; j < 4; ++j) {
                int sj = __shfl(sB, j, 4);
                uint2 uu = hp[sj * 4 + q];
                ax += bf16lo(uu.x); ay += bf16hi(uu.x); az += bf16lo(uu.y); aw += bf16hi(uu.y);
            }
#pragma unroll
            for (int j = 0; j < 4; ++j) {
                int sj = __shfl(sC, j, 4);
                uint2 uu = hp[sj * 4 + q];
                ax += bf16lo(uu.x); ay += bf16hi(uu.x); az += bf16lo(uu.y); aw += bf16hi(uu.y);
            }
#pragma unroll
            for (int j = 0; j < 4; ++j) {
                int sj = __shfl(sD, j, 4);
                uint2 uu = hp[sj * 4 + q];
                ax += bf16lo(uu.x); ay += bf16hi(uu.x); az += bf16lo(uu.y); aw += bf16hi(uu.y);
            }
        }
        for (; i + 8 <= hi; i += 8) {
            int sA = csrf[i + q], sB = csrf[i + 4 + q];
#pragma unroll
            for (int j = 0; j < 4; ++j) {
                int sj = __shfl(sA, j, 4);
                uint2 uu = hp[sj * 4 + q];
                ax += bf16lo(uu.x); ay += bf16hi(uu.x); az += bf16lo(uu.y); aw += bf16hi(uu.y);
            }
#pragma unroll
            for (int j = 0; j < 4; ++j) {
                int sj = __shfl(sB, j, 4);
                uint2 uu = hp[sj * 4 + q];
                ax += bf16lo(uu.x); ay += bf16hi(uu.x); az += bf16lo(uu.y); aw += bf16hi(uu.y);
            }
        }
        for (; i < hi; ++i) {
            uint2 uu = hp[csrf[i] * 4 + q];
            ax += bf16lo(uu.x); ay += bf16hi(uu.x); az += bf16lo(uu.y); aw += bf16hi(uu.y);
        }
        if (c > CAP) {
            int ce = c - CAP; if (ce > EXT) ce = EXT;
            for (int j = 0; j < ce; ++j) {
                uint2 uu = hp[ext[n * EXT + j] * 4 + q];
                ax += bf16lo(uu.x); ay += bf16hi(uu.x); az += bf16lo(uu.y); aw += bf16hi(uu.y);
            }
        }
        float dvn = dinv[n];
        hx = fmaxf(ax * dvn + sb2[q * 4 + 0], 0.f);
        hy = fmaxf(ay * dvn + sb2[q * 4 + 1], 0.f);
        hz = fmaxf(az * dvn + sb2[q * 4 + 2], 0.f);
        hw = fmaxf(aw * dvn + sb2[q * 4 + 3], 0.f);
    }
    float* row = &sh[ln * 17 + q * 4];
    row[0] = hx; row[1] = hy; row[2] = hz; row[3] = hw;
    __syncthreads();
    if (valid) {
        int g = sg[ln];
        bool lead = (ln == 0) || (sg[ln - 1] != g);
        if (lead) {                            // this 4-lane group reduces its run
            float a0 = 0.f, a1 = 0.f, a2 = 0.f, a3 = 0.f;
            int len = 0;
            for (int j = ln; j < 64 && sg[j] == g; ++j) {
                const float* r = &sh[j * 17 + q * 4];
                a0 += r[0]; a1 += r[1]; a2 += r[2]; a3 += r[3];
                ++len;
            }
            atomicAdd(&psum[g * HID + q * 4 + 0], a0);
            atomicAdd(&psum[g * HID + q * 4 + 1], a1);
            atomicAdd(&psum[g * HID + q * 4 + 2], a2);
            atomicAdd(&psum[g * HID + q * 4 + 3], a3);
            if (q == 0) atomicAdd(&pcnt[g], (float)len);
        }
    }
}

// logits = (psum / max(pcnt,1)) @ Wc + bc
__global__ void k_logits(const float* __restrict__ psum, const float* __restrict__ pcnt,
                         const float* __restrict__ Wc, const float* __restrict__ bc,
                         float* __restrict__ outp) {
    int t = blockIdx.x * blockDim.x + threadIdx.x;
    if (t >= N_GRAPHS * LABELS) return;
    int g = t / LABELS, l = t % LABELS;
    float c = fmaxf(pcnt[g], 1.0f);
    float acc = bc[l];
#pragma unroll
    for (int k = 0; k < HID; ++k) acc += (psum[g * HID + k] / c) * Wc[k * LABELS + l];
    outp[t] = acc;
}

extern "C" void kernel_launch(void* const* d_in, const int* in_sizes, int n_in,
                              void* d_out, int out_size, void* d_ws, size_t ws_size,
                              hipStream_t stream) {
    const int*   x     = (const int*)d_in[0];
    const int*   ei    = (const int*)d_in[1];
    const int*   batch = (const int*)d_in[2];
    const float* emb   = (const float*)d_in[3];
    const float* W1    = (const float*)d_in[4];
    const float* b1    = (const float*)d_in[5];
    const float* W2    = (const float*)d_in[6];
    const float* b2    = (const float*)d_in[7];
    const float* Wc    = (const float*)d_in[8];
    const float* bc    = (const float*)d_in[9];
    float* outp = (float*)d_out;

    // workspace layout ~43 MB; psum/pcnt/bcur contiguous -> one memset (cnt is
    // fully written by k_fill, no memset needed).
    float*    psum  = (float*)d_ws;                      // N_GRAPHS*HID
    float*    pcnt  = psum + N_GRAPHS * HID;             // N_GRAPHS
    int*      bcur  = (int*)(pcnt + N_GRAPHS);           // NB*NSUB append cursors
    int*      cnt   = bcur + NB * NSUB;                  // N_NODES true degree
    float*    dinv  = (float*)(cnt + N_NODES);           // N_NODES
    unsigned* xd32  = (unsigned*)(dinv + N_NODES);       // N_NODES packed (x<<16)|bf16(dinv)
    unsigned* hws16 = xd32 + N_NODES;                    // N_NODES*8 bf16x2 (8 B aligned)
    float*    table = (float*)(hws16 + (size_t)N_NODES * 8); // VOCAB*HID
    int*      csrf  = (int*)(table + VOCAB * HID);       // NB*BREG (entry buf, then CSR)
    int*      ext   = csrf + (size_t)NB * BREG;          // N_NODES*EXT cold overflow

    const int* srcp = ei;            // edge_index row 0
    const int* dstp = ei + N_EDGES;  // edge_index row 1

    (void)hipMemsetAsync(psum, 0,
        (N_GRAPHS * HID + N_GRAPHS + NB * NSUB) * sizeof(int), stream);

    const int BINBLK = (N_EDGES + BCHUNK - 1) / BCHUNK;  // 782
    k_bin     <<<BINBLK, 256, 0, stream>>>(srcp, dstp, bcur, csrf);
    k_fill    <<<NB, 256, 0, stream>>>(bcur, csrf, ext, cnt);
    k_dinv2   <<<(N_NODES + 255) / 256, 256, 0, stream>>>(cnt, x, dinv, xd32);
    k_table   <<<(VOCAB * HID + 255) / 256, 256, 0, stream>>>(emb, W1, table);
    k_gather_t<<<(N_NODES * 8) / 256, 256, 0, stream>>>(cnt, csrf, ext, xd32, dinv, table, b1, W2, hws16);
    k_gather2 <<<(N_NODES * 4 + 255) / 256, 256, 0, stream>>>(cnt, csrf, ext, dinv, hws16, batch, b2, psum, pcnt);
    k_logits  <<<(N_GRAPHS * LABELS + 255) / 256, 256, 0, stream>>>(psum, pcnt, Wc, bc, outp);
}

// Round 7
// 205.275 us; speedup vs baseline: 1.1036x; 1.1036x over previous
//
#include <hip/hip_runtime.h>

#define N_NODES 100000
#define N_EDGES 3200000
#define N_GRAPHS 512
#define VOCAB 128
#define HID 16
#define LABELS 10
#define CAP 64                  // main slots/node
#define EXT 32                  // overflow slots/node (cold)
#define TS 17                   // LDS table row stride (bank de-alias)

// ---- binned CSR build ----
#define BSH 9                   // 512 nodes per bucket (long runs, R6-validated)
#define BNODES 512
#define NB 196                  // ceil(N_NODES/512)
#define NSUB 8                  // XCD-local sub-tails (blockIdx&7 ~ XCD)
#define SUBCAP 4096             // entries per (bucket,sub)
#define BREG (BNODES * CAP)     // 32768 ints per bucket region == NSUB*SUBCAP
#define EPT 8                   // edges per thread in k_bin (R7: 512 thr)
#define BCHUNK 4096             // edges per k_bin block (512 thr x 8)

typedef int vint4 __attribute__((ext_vector_type(4)));  // native vec for NT loads

__device__ __forceinline__ unsigned bf16rne(float f) {
    unsigned u = __float_as_uint(f);
    return (u + 0x7fffu + ((u >> 16) & 1u)) >> 16;
}
__device__ __forceinline__ float bf16lo(unsigned p) { return __uint_as_float(p << 16); }
__device__ __forceinline__ float bf16hi(unsigned p) { return __uint_as_float(p & 0xffff0000u); }

// Pass 1: bin edges by dst>>9 via LDS counting sort, write bucket-sorted runs.
// R6 lesson: WRITE is fixed (18.5 MB ~ payload) but Occupancy 25% == the grid
// limit (782 blk x 4 waves) -> latency-bound at 730 GB/s. R7: 512 threads x
// EPT 8 keeps BCHUNK/runs/write-amp IDENTICAL while doubling waves/CU to ~24.
// Block 0 also computes table = emb @ W1 (fused k_table: one less launch).
__global__ void k_bin(const int* __restrict__ src, const int* __restrict__ dst,
                      int* __restrict__ bcur, int* __restrict__ ebuf,
                      const float* __restrict__ emb, const float* __restrict__ W1,
                      float* __restrict__ table) {
    __shared__ int scnt[NB];              // histogram, then exclusive prefix (in-place)
    __shared__ int gbase[NB];             // absolute (padded) ebuf base for this block's run
    __shared__ int sent[BCHUNK];          // compact sorted entries
    int t = threadIdx.x;
    int sub = blockIdx.x & (NSUB - 1);
    if (blockIdx.x == 0) {                // fused k_table (independent global work)
        for (int i = t; i < VOCAB * HID; i += 512) {
            int v = i >> 4, k = i & 15;
            float acc = 0.f;
#pragma unroll
            for (int j = 0; j < HID; ++j) acc += emb[v * HID + j] * W1[j * HID + k];
            table[i] = acc;
        }
    }
    for (int i = t; i < NB; i += 512) scnt[i] = 0;
    int e0 = blockIdx.x * BCHUNK + t * EPT;
    bool val = e0 < N_EDGES;              // N_EDGES % 8 == 0 -> whole-thread validity
    int dd[EPT], ss[EPT];
    if (val) {
        const vint4* dp = (const vint4*)(dst + e0);
        const vint4* sp = (const vint4*)(src + e0);
#pragma unroll
        for (int q = 0; q < 2; ++q) {
            vint4 d4 = __builtin_nontemporal_load(dp + q);
            vint4 s4 = __builtin_nontemporal_load(sp + q);
            dd[q * 4 + 0] = d4.x; dd[q * 4 + 1] = d4.y; dd[q * 4 + 2] = d4.z; dd[q * 4 + 3] = d4.w;
            ss[q * 4 + 0] = s4.x; ss[q * 4 + 1] = s4.y; ss[q * 4 + 2] = s4.z; ss[q * 4 + 3] = s4.w;
        }
    }
    __syncthreads();                      // scnt zeroed
    int rk[EPT];
    if (val) {
#pragma unroll
        for (int j = 0; j < EPT; ++j) rk[j] = atomicAdd(&scnt[dd[j] >> BSH], 1);
    }
    __syncthreads();                      // histogram complete
    // single-wave exclusive scan: lane t owns buckets [4t, 4t+4); NB = 49*4
    if (t < 64) {
        int b0 = t * 4;
        int c0 = 0, c1 = 0, c2 = 0, c3 = 0;
        if (b0 < NB) { c0 = scnt[b0]; c1 = scnt[b0 + 1]; c2 = scnt[b0 + 2]; c3 = scnt[b0 + 3]; }
        int lsum = c0 + c1 + c2 + c3;
        int x = lsum;
#pragma unroll
        for (int d = 1; d < 64; d <<= 1) {
            int y = __shfl_up(x, d);
            if (t >= d) x += y;
        }
        int excl = x - lsum;              // exclusive base for this lane's buckets
        if (b0 < NB) {
            int cc[4] = {c0, c1, c2, c3};
#pragma unroll
            for (int q = 0; q < 4; ++q) {
                int b = b0 + q;
                scnt[b] = excl;           // in-place: now the exclusive prefix
                if (cc[q] > 0) {
                    int r = (cc[q] + 3) & ~3;            // padded reservation (x4)
                    int g = atomicAdd(&bcur[b * NSUB + sub], r);
                    gbase[b] = b * BREG + sub * SUBCAP + g;   // 16B-aligned
                }
                excl += cc[q];
            }
        }
    }
    __syncthreads();                      // prefix/gbase ready
    if (val) {
#pragma unroll
        for (int j = 0; j < EPT; ++j) {
            int d = dd[j], b = d >> BSH;
            sent[scnt[b] + rk[j]] = ((d & (BNODES - 1)) << 17) | ss[j];
        }
    }
    __syncthreads();                      // sorted stage ready
    int nval = N_EDGES - blockIdx.x * BCHUNK;
    if (nval > BCHUNK) nval = BCHUNK;
    if (t < 2 * NB) {                     // 2 threads per bucket run, interleaved int4s
        int b = t >> 1, half = t & 1;
        int base = scnt[b];
        int cend = (b + 1 < NB) ? scnt[b + 1] : nval;
        int c = cend - base;
        if (c > 0) {
            int g = gbase[b];
            int lim = b * BREG + (sub + 1) * SUBCAP;
            for (int j = half * 4; j < c; j += 8) {
                if (g + j + 4 > lim) break;   // overflow guard (P ~ 0)
                int4 v;
                v.x = sent[base + j];
                v.y = (j + 1 < c) ? sent[base + j + 1] : -1;
                v.z = (j + 2 < c) ? sent[base + j + 2] : -1;
                v.w = (j + 3 < c) ? sent[base + j + 3] : -1;
                *(int4*)(ebuf + g + j) = v;   // aligned 16B, dense line fill
            }
        }
    }
}

// Pass 2: one block per 512-node bucket, 1024 threads (R7: 4x the R6 wave
// count; 130 KB slab R6-validated). Scatter entries into LDS CSR slab, write
// used slots coalesced, emit cnt AND (fused k_dinv2) dinv/xd32 from the
// in-LDS degree. Reads its entry region BEFORE overwriting it.
__global__ void k_fill(const int* __restrict__ bcur, int* __restrict__ csrf,
                       int* __restrict__ ext, int* __restrict__ cnt,
                       const int* __restrict__ x, float* __restrict__ dinv,
                       unsigned* __restrict__ xd32) {
    __shared__ int stage[BREG];                  // 128 KB
    __shared__ int cl[BNODES];                   // 2 KB
    int b = blockIdx.x, t = threadIdx.x;
    int nb0 = b << BSH;
    int nn = N_NODES - nb0; if (nn > BNODES) nn = BNODES;
    if (t < BNODES) cl[t] = 0;
    __syncthreads();
    const int* ebase = csrf + (size_t)b * BREG;
    for (int sub = 0; sub < NSUB; ++sub) {
        int m = bcur[b * NSUB + sub]; if (m > SUBCAP) m = SUBCAP;
        const int* ep = ebase + sub * SUBCAP;
        for (int i = t; i < m; i += 1024) {
            int e2 = ep[i];
            if (e2 == -1) continue;                  // pad sentinel
            int dl = ((unsigned)e2) >> 17, s = e2 & 0x1FFFF;
            int c = atomicAdd(&cl[dl], 1);
            if (c < CAP)            stage[(dl << 6) + c] = s;
            else if (c < CAP + EXT) ext[(size_t)(nb0 + dl) * EXT + (c - CAP)] = s;
            // c >= CAP+EXT unreachable (P ~ 0)
        }
    }
    __syncthreads();
    int4* o4 = (int4*)(csrf + (size_t)b * BREG);
    const int4* s4 = (const int4*)stage;
    {
        int dl = t >> 1;                             // 2 threads per node, one pass
        int m4 = (cl[dl] + 3) >> 2;                  // used int4s (garbage never read)
        for (int j = (t & 1); j < m4; j += 2)
            o4[(dl << 4) + j] = s4[(dl << 4) + j];
    }
    if (t < nn) {                                    // fused k_dinv2
        int c = cl[t];
        cnt[nb0 + t] = c;
        float dv = rsqrtf((float)c + 1.0f);          // +1 = self-loop
        dinv[nb0 + t] = dv;
        xd32[nb0 + t] = ((unsigned)x[nb0 + t] << 16) | bf16rne(dv);
    }
}

// FUSED layer-1 aggregation + update, 8 lanes/node (lane k owns features k, k+8).
// 16-wide main loop: two independent {csrf load -> xd32 gather} chains.
__global__ void k_gather_t(const int* __restrict__ cnt, const int* __restrict__ csrf,
                           const int* __restrict__ ext,
                           const unsigned* __restrict__ xd32, const float* __restrict__ dinv,
                           const float* __restrict__ table,
                           const float* __restrict__ b1, const float* __restrict__ W2,
                           unsigned* __restrict__ hws16) {
    __shared__ float tbl[VOCAB * TS];
    __shared__ float sW[HID * HID];
    __shared__ float sb[HID];
    __shared__ float sh[32][HID + 1];
    for (int i = threadIdx.x; i < VOCAB * HID; i += 256)
        tbl[(i / HID) * TS + (i % HID)] = table[i];
    if (threadIdx.x < HID * HID) sW[threadIdx.x] = W2[threadIdx.x];
    if (threadIdx.x < HID) sb[threadIdx.x] = b1[threadIdx.x];
    __syncthreads();
    int t = blockIdx.x * 256 + threadIdx.x;
    int n = t >> 3, k = t & 7, nl = threadIdx.x >> 3;   // 32 node-groups/block
    float dvn = dinv[n];
    unsigned selfp = xd32[n];
    int vs = (selfp >> 16) * TS;
    float a0 = tbl[vs + k] * dvn, a1 = tbl[vs + k + 8] * dvn;   // self-loop
    int c = cnt[n];
    int cm = c < CAP ? c : CAP;
    int lo = n * CAP, hi = lo + cm;
    int i = lo;
    for (; i + 16 <= hi; i += 16) {
        int sa = csrf[i + k];             // chain A
        int sb_ = csrf[i + 8 + k];        // chain B (independent)
        unsigned pa = xd32[sa];
        unsigned pb = xd32[sb_];
#pragma unroll
        for (int j = 0; j < 8; ++j) {
            unsigned pj = __shfl(pa, j, 8);
            float w = bf16lo(pj);
            int v = (pj >> 16) * TS;
            a0 += tbl[v + k] * w;         a1 += tbl[v + k + 8] * w;
        }
#pragma unroll
        for (int j = 0; j < 8; ++j) {
            unsigned pj = __shfl(pb, j, 8);
            float w = bf16lo(pj);
            int v = (pj >> 16) * TS;
            a0 += tbl[v + k] * w;         a1 += tbl[v + k + 8] * w;
        }
    }
    for (; i + 8 <= hi; i += 8) {
        int s = csrf[i + k];
        unsigned p = xd32[s];
#pragma unroll
        for (int j = 0; j < 8; ++j) {
            unsigned pj = __shfl(p, j, 8);
            float w = bf16lo(pj);
            int v = (pj >> 16) * TS;
            a0 += tbl[v + k] * w;         a1 += tbl[v + k + 8] * w;
        }
    }
    for (; i < hi; ++i) {
        unsigned p = xd32[csrf[i]];
        float w = bf16lo(p);
        int v = (p >> 16) * TS;
        a0 += tbl[v + k] * w;             a1 += tbl[v + k + 8] * w;
    }
    if (c > CAP) {                        // rare overflow tail
        int ce = c - CAP; if (ce > EXT) ce = EXT;
        for (int j = 0; j < ce; ++j) {
            unsigned p = xd32[ext[n * EXT + j]];
            float w = bf16lo(p);
            int v = (p >> 16) * TS;
            a0 += tbl[v + k] * w;         a1 += tbl[v + k + 8] * w;
        }
    }
    sh[nl][k]     = fmaxf(a0 * dvn + sb[k], 0.f);      // h1[n,k]
    sh[nl][k + 8] = fmaxf(a1 * dvn + sb[k + 8], 0.f);  // h1[n,k+8]
    __syncthreads();
    float o0 = 0.f, o1 = 0.f;
#pragma unroll
    for (int j = 0; j < HID; ++j) {
        float h = sh[nl][j];
        o0 += h * sW[j * HID + k];
        o1 += h * sW[j * HID + k + 8];
    }
    o0 *= dvn; o1 *= dvn;
    float p0 = __shfl_xor(o0, 1), p1 = __shfl_xor(o1, 1);  // partner features k^1
    if ((k & 1) == 0) {                   // even lane packs (k,k+1) and (k+8,k+9)
        hws16[n * 8 + (k >> 1)]     = (bf16rne(p0) << 16) | bf16rne(o0);
        hws16[n * 8 + 4 + (k >> 1)] = (bf16rne(p1) << 16) | bf16rne(o1);
    }
}

// FUSED layer-2 aggregation + relu + mean-pool accumulation. 4 lanes/node,
// 16-wide main loop (four independent gather chains). Batch sorted -> leader
// lanes reduce graph runs in LDS, one atomicAdd per (run x 4 features).
__global__ void k_gather2(const int* __restrict__ cnt, const int* __restrict__ csrf,
                          const int* __restrict__ ext,
                          const float* __restrict__ dinv, const unsigned* __restrict__ hws16,
                          const int* __restrict__ batch, const float* __restrict__ b2,
                          float* __restrict__ psum, float* __restrict__ pcnt) {
    __shared__ float sh[64 * 17];              // 64 nodes x 16 feats, pad 17
    __shared__ int   sg[64];                   // graph id per node slot (-1 invalid)
    __shared__ float sb2[16];
    int idx = blockIdx.x * 256 + threadIdx.x;
    int n = idx >> 2, q = idx & 3, ln = threadIdx.x >> 2;
    bool valid = n < N_NODES;
    if (threadIdx.x < 16) sb2[threadIdx.x] = b2[threadIdx.x];
    if (q == 0) sg[ln] = valid ? batch[n] : -1;
    __syncthreads();
    float hx = 0.f, hy = 0.f, hz = 0.f, hw = 0.f;
    if (valid) {
        const uint2* hp = (const uint2*)hws16; // 4 uint2 per node row
        uint2 u = hp[n * 4 + q];
        float ax = bf16lo(u.x), ay = bf16hi(u.x), az = bf16lo(u.y), aw = bf16hi(u.y);
        int c = cnt[n];
        int cm = c < CAP ? c : CAP;
        int lo = n * CAP, hi = lo + cm;
        int i = lo;
        for (; i + 16 <= hi; i += 16) {
            int sA = csrf[i + q],      sB = csrf[i + 4 + q];
            int sC = csrf[i + 8 + q],  sD = csrf[i + 12 + q];
#pragma unroll
            for (int j = 0; j < 4; ++j) {
                int sj = __shfl(sA, j, 4);
                uint2 uu = hp[sj * 4 + q];
                ax += bf16lo(uu.x); ay += bf16hi(uu.x); az += bf16lo(uu.y); aw += bf16hi(uu.y);
            }
#pragma unroll
            for (int j = 0; j < 4; ++j) {
                int sj = __shfl(sB, j, 4);
                uint2 uu = hp[sj * 4 + q];
                ax += bf16lo(uu.x); ay += bf16hi(uu.x); az += bf16lo(uu.y); aw += bf16hi(uu.y);
            }
#pragma unroll
            for (int j = 0; j < 4; ++j) {
                int sj = __shfl(sC, j, 4);
                uint2 uu = hp[sj * 4 + q];
                ax += bf16lo(uu.x); ay += bf16hi(uu.x); az += bf16lo(uu.y); aw += bf16hi(uu.y);
            }
#pragma unroll
            for (int j = 0; j < 4; ++j) {
                int sj = __shfl(sD, j, 4);
                uint2 uu = hp[sj * 4 + q];
                ax += bf16lo(uu.x); ay += bf16hi(uu.x); az += bf16lo(uu.y); aw += bf16hi(uu.y);
            }
        }
        for (; i + 8 <= hi; i += 8) {
            int sA = csrf[i + q], sB = csrf[i + 4 + q];
#pragma unroll
            for (int j = 0; j < 4; ++j) {
                int sj = __shfl(sA, j, 4);
                uint2 uu = hp[sj * 4 + q];
                ax += bf16lo(uu.x); ay += bf16hi(uu.x); az += bf16lo(uu.y); aw += bf16hi(uu.y);
            }
#pragma unroll
            for (int j = 0; j < 4; ++j) {
                int sj = __shfl(sB, j, 4);
                uint2 uu = hp[sj * 4 + q];
                ax += bf16lo(uu.x); ay += bf16hi(uu.x); az += bf16lo(uu.y); aw += bf16hi(uu.y);
            }
        }
        for (; i < hi; ++i) {
            uint2 uu = hp[csrf[i] * 4 + q];
            ax += bf16lo(uu.x); ay += bf16hi(uu.x); az += bf16lo(uu.y); aw += bf16hi(uu.y);
        }
        if (c > CAP) {
            int ce = c - CAP; if (ce > EXT) ce = EXT;
            for (int j = 0; j < ce; ++j) {
                uint2 uu = hp[ext[n * EXT + j] * 4 + q];
                ax += bf16lo(uu.x); ay += bf16hi(uu.x); az += bf16lo(uu.y); aw += bf16hi(uu.y);
            }
        }
        float dvn = dinv[n];
        hx = fmaxf(ax * dvn + sb2[q * 4 + 0], 0.f);
        hy = fmaxf(ay * dvn + sb2[q * 4 + 1], 0.f);
        hz = fmaxf(az * dvn + sb2[q * 4 + 2], 0.f);
        hw = fmaxf(aw * dvn + sb2[q * 4 + 3], 0.f);
    }
    float* row = &sh[ln * 17 + q * 4];
    row[0] = hx; row[1] = hy; row[2] = hz; row[3] = hw;
    __syncthreads();
    if (valid) {
        int g = sg[ln];
        bool lead = (ln == 0) || (sg[ln - 1] != g);
        if (lead) {                            // this 4-lane group reduces its run
            float a0 = 0.f, a1 = 0.f, a2 = 0.f, a3 = 0.f;
            int len = 0;
            for (int j = ln; j < 64 && sg[j] == g; ++j) {
                const float* r = &sh[j * 17 + q * 4];
                a0 += r[0]; a1 += r[1]; a2 += r[2]; a3 += r[3];
                ++len;
            }
            atomicAdd(&psum[g * HID + q * 4 + 0], a0);
            atomicAdd(&psum[g * HID + q * 4 + 1], a1);
            atomicAdd(&psum[g * HID + q * 4 + 2], a2);
            atomicAdd(&psum[g * HID + q * 4 + 3], a3);
            if (q == 0) atomicAdd(&pcnt[g], (float)len);
        }
    }
}

// logits = (psum / max(pcnt,1)) @ Wc + bc
__global__ void k_logits(const float* __restrict__ psum, const float* __restrict__ pcnt,
                         const float* __restrict__ Wc, const float* __restrict__ bc,
                         float* __restrict__ outp) {
    int t = blockIdx.x * blockDim.x + threadIdx.x;
    if (t >= N_GRAPHS * LABELS) return;
    int g = t / LABELS, l = t % LABELS;
    float c = fmaxf(pcnt[g], 1.0f);
    float acc = bc[l];
#pragma unroll
    for (int k = 0; k < HID; ++k) acc += (psum[g * HID + k] / c) * Wc[k * LABELS + l];
    outp[t] = acc;
}

extern "C" void kernel_launch(void* const* d_in, const int* in_sizes, int n_in,
                              void* d_out, int out_size, void* d_ws, size_t ws_size,
                              hipStream_t stream) {
    const int*   x     = (const int*)d_in[0];
    const int*   ei    = (const int*)d_in[1];
    const int*   batch = (const int*)d_in[2];
    const float* emb   = (const float*)d_in[3];
    const float* W1    = (const float*)d_in[4];
    const float* b1    = (const float*)d_in[5];
    const float* W2    = (const float*)d_in[6];
    const float* b2    = (const float*)d_in[7];
    const float* Wc    = (const float*)d_in[8];
    const float* bc    = (const float*)d_in[9];
    float* outp = (float*)d_out;

    // workspace layout ~43 MB; psum/pcnt/bcur contiguous -> one memset (cnt is
    // fully written by k_fill, no memset needed).
    float*    psum  = (float*)d_ws;                      // N_GRAPHS*HID
    float*    pcnt  = psum + N_GRAPHS * HID;             // N_GRAPHS
    int*      bcur  = (int*)(pcnt + N_GRAPHS);           // NB*NSUB append cursors
    int*      cnt   = bcur + NB * NSUB;                  // N_NODES true degree
    float*    dinv  = (float*)(cnt + N_NODES);           // N_NODES
    unsigned* xd32  = (unsigned*)(dinv + N_NODES);       // N_NODES packed (x<<16)|bf16(dinv)
    unsigned* hws16 = xd32 + N_NODES;                    // N_NODES*8 bf16x2 (8 B aligned)
    float*    table = (float*)(hws16 + (size_t)N_NODES * 8); // VOCAB*HID
    int*      csrf  = (int*)(table + VOCAB * HID);       // NB*BREG (entry buf, then CSR)
    int*      ext   = csrf + (size_t)NB * BREG;          // N_NODES*EXT cold overflow

    const int* srcp = ei;            // edge_index row 0
    const int* dstp = ei + N_EDGES;  // edge_index row 1

    (void)hipMemsetAsync(psum, 0,
        (N_GRAPHS * HID + N_GRAPHS + NB * NSUB) * sizeof(int), stream);

    const int BINBLK = (N_EDGES + BCHUNK - 1) / BCHUNK;  // 782
    k_bin     <<<BINBLK, 512, 0, stream>>>(srcp, dstp, bcur, csrf, emb, W1, table);
    k_fill    <<<NB, 1024, 0, stream>>>(bcur, csrf, ext, cnt, x, dinv, xd32);
    k_gather_t<<<(N_NODES * 8) / 256, 256, 0, stream>>>(cnt, csrf, ext, xd32, dinv, table, b1, W2, hws16);
    k_gather2 <<<(N_NODES * 4 + 255) / 256, 256, 0, stream>>>(cnt, csrf, ext, dinv, hws16, batch, b2, psum, pcnt);
    k_logits  <<<(N_GRAPHS * LABELS + 255) / 256, 256, 0, stream>>>(psum, pcnt, Wc, bc, outp);
}